// Round 5
// baseline (294.842 us; speedup 1.0000x reference)
//
#include <hip/hip_runtime.h>
#include <math.h>

#define Bsz 64
#define Tn 200
#define NUMC 2000
#define DS 128
#define SM 50
#define NTOK (Bsz*Tn)
#define MPG 5        // m-rows per wave in scan
#define NWV 10       // waves per scan block (NWV*MPG == SM)
#define CH 20        // timesteps per LDS-reduce chunk

typedef __attribute__((ext_vector_type(8))) short bfrag;
typedef __attribute__((ext_vector_type(4))) float f32x4;
typedef __attribute__((ext_vector_type(4))) unsigned int u32x4;

__device__ __forceinline__ unsigned short f2bf(float x) {
    unsigned int u = __builtin_bit_cast(unsigned int, x);
    u = u + 0x7fffu + ((u >> 16) & 1u);   // RNE
    return (unsigned short)(u >> 16);
}
__device__ __forceinline__ unsigned int pack2(float a, float b) {
    return (unsigned int)f2bf(a) | ((unsigned int)f2bf(b) << 16);
}
__device__ __forceinline__ bfrag mk_frag(f32x4 x, f32x4 y) {
    u32x4 t;
    t[0] = pack2(x[0], x[1]); t[1] = pack2(x[2], x[3]);
    t[2] = pack2(y[0], y[1]); t[3] = pack2(y[2], y[3]);
    return __builtin_bit_cast(bfrag, t);
}

// fast transcendentals: v_exp_f32 / v_rcp_f32 (~1e-6 rel err, invisible at bf16 grade)
__device__ __forceinline__ float fast_exp(float x)  { return __builtin_amdgcn_exp2f(x * 1.44269504f); }
__device__ __forceinline__ float fast_rcp(float x)  { return __builtin_amdgcn_rcpf(x); }
__device__ __forceinline__ float fast_sigmoid(float x) { return fast_rcp(1.f + fast_exp(-x)); }
__device__ __forceinline__ float fast_tanh(float x) { return 1.f - 2.f * fast_rcp(fast_exp(2.f * x) + 1.f); }

__device__ __forceinline__ void load_group(const bfrag* __restrict__ B, int nt0, int L, bfrag bf[4][4]) {
    #pragma unroll
    for (int t = 0; t < 4; t++)
        #pragma unroll
        for (int ki = 0; ki < 4; ki++)
            bf[t][ki] = B[(size_t)((nt0 + t) * 4 + ki) * 64 + L];
}
__device__ __forceinline__ void mfma_group(const bfrag A[4], const bfrag bf[4][4], f32x4 acc[4]) {
    #pragma unroll
    for (int ki = 0; ki < 4; ki++)
        #pragma unroll
        for (int t = 0; t < 4; t++)
            acc[t] = __builtin_amdgcn_mfma_f32_16x16x32_bf16(A[ki], bf[t][ki], acc[t], 0, 0, 0);
}

// ---------------- K0: cast weights into MFMA b-frag block layout ----------------
// lane L holds W[n = nt*16 + (L&15)][k = ki*32 + (L>>4)*8 + j], j=0..7.
// Bea: rows 0-127 = e_W, 128-255 = a_W          (16 n-tiles)
// Bkm: rows 0-127 = f_W[:,128:256], 128-177 = Mk, 178-191 = 0   (12 n-tiles)
// Bf0: rows 0-127 = f_W[:,0:128]                (8 n-tiles)
__global__ __launch_bounds__(256) void k0_cast(
    const float* __restrict__ eW, const float* __restrict__ aW,
    const float* __restrict__ fW, const float* __restrict__ Mk,
    unsigned int* __restrict__ BeaU, unsigned int* __restrict__ BkmU,
    unsigned int* __restrict__ Bf0U)
{
    const int g = blockIdx.x * 256 + threadIdx.x;
    if (g >= 9216) return;
    int gm, mat;
    unsigned int* dst;
    if (g < 4096)      { mat = 0; gm = g;        dst = BeaU; }
    else if (g < 7168) { mat = 1; gm = g - 4096; dst = BkmU; }
    else               { mat = 2; gm = g - 7168; dst = Bf0U; }
    const int nt = gm >> 8, r = gm & 255, ki = r >> 6, L = r & 63;
    const int n = nt * 16 + (L & 15);
    const int k = ki * 32 + (L >> 4) * 8;

    const float* src = nullptr;
    if (mat == 0) {
        src = (n < 128) ? (eW + (size_t)n * DS + k) : (aW + (size_t)(n - 128) * DS + k);
    } else if (mat == 1) {
        if (n < 128)      src = fW + (size_t)n * (2 * DS) + DS + k;
        else if (n < 128 + SM) src = Mk + (size_t)(n - 128) * DS + k;
    } else {
        src = fW + (size_t)n * (2 * DS) + k;
    }
    float v[8];
    #pragma unroll
    for (int j = 0; j < 8; j++) v[j] = src ? src[j] : 0.f;
    u32x4 o;
    o[0] = pack2(v[0], v[1]); o[1] = pack2(v[2], v[3]);
    o[2] = pack2(v[4], v[5]); o[3] = pack2(v[6], v[7]);
    ((u32x4*)dst)[gm] = o;
}

// ---------------- K1: 1-wave blocks; bid<800 -> EA wave, else KM wave ----------------
__global__ __launch_bounds__(64) void k1_gemm(
    const int* __restrict__ skill, const int* __restrict__ answer,
    const float* __restrict__ k_emb, const float* __restrict__ v_emb,
    const unsigned int* __restrict__ BeaU, const unsigned int* __restrict__ BkmU,
    const float* __restrict__ eB, const float* __restrict__ aB,
    float* __restrict__ w_buf, float* __restrict__ e_buf,
    float* __restrict__ a_buf, float* __restrict__ kp_buf)
{
    const int bid = blockIdx.x;
    const int L = threadIdx.x, L15 = L & 15, quad = L >> 4;

    if (bid < NTOK/16) {
        // ===== EA wave: V @ Bea^T -> e (tiles 0-7, sigmoid), a (tiles 8-15, tanh) =====
        const int tok0 = bid * 16;
        const int tokA = tok0 + L15;
        const int tokD0 = tok0 + quad * 4;

        const bfrag* Bea = (const bfrag*)BeaU;
        bfrag bfA[4][4], bfB[4][4];
        load_group(Bea, 0, L, bfA);
        load_group(Bea, 4, L, bfB);

        const int s  = skill[tokA];
        const int an = answer[tokA];
        const int ax = (an == 2) ? 1 : an;
        const float* vp = v_emb + ((size_t)(s + NUMC * ax)) * DS + quad * 8;
        bfrag Vf[4];
        #pragma unroll
        for (int ki = 0; ki < 4; ki++) {
            const f32x4* a = (const f32x4*)(vp + ki * 32);
            Vf[ki] = mk_frag(a[0], a[1]);
        }

        f32x4 acc[4];
        #pragma unroll
        for (int t = 0; t < 4; t++) acc[t] = (f32x4){0.f,0.f,0.f,0.f};
        mfma_group(Vf, bfA, acc);
        load_group(Bea, 8, L, bfA);
        #pragma unroll
        for (int t = 0; t < 4; t++) {
            const int n = t * 16 + L15;
            const float bias = eB[n];
            #pragma unroll
            for (int reg = 0; reg < 4; reg++)
                e_buf[(size_t)(tokD0 + reg) * DS + n] = fast_sigmoid(acc[t][reg] + bias);
        }

        #pragma unroll
        for (int t = 0; t < 4; t++) acc[t] = (f32x4){0.f,0.f,0.f,0.f};
        mfma_group(Vf, bfB, acc);
        load_group(Bea, 12, L, bfB);
        #pragma unroll
        for (int t = 0; t < 4; t++) {
            const int n = (4 + t) * 16 + L15;
            const float bias = eB[n];
            #pragma unroll
            for (int reg = 0; reg < 4; reg++)
                e_buf[(size_t)(tokD0 + reg) * DS + n] = fast_sigmoid(acc[t][reg] + bias);
        }

        #pragma unroll
        for (int t = 0; t < 4; t++) acc[t] = (f32x4){0.f,0.f,0.f,0.f};
        mfma_group(Vf, bfA, acc);
        #pragma unroll
        for (int t = 0; t < 4; t++) {
            const int n = t * 16 + L15;
            const float bias = aB[n];
            #pragma unroll
            for (int reg = 0; reg < 4; reg++)
                a_buf[(size_t)(tokD0 + reg) * DS + n] = fast_tanh(acc[t][reg] + bias);
        }

        #pragma unroll
        for (int t = 0; t < 4; t++) acc[t] = (f32x4){0.f,0.f,0.f,0.f};
        mfma_group(Vf, bfB, acc);
        #pragma unroll
        for (int t = 0; t < 4; t++) {
            const int n = (4 + t) * 16 + L15;
            const float bias = aB[n];
            #pragma unroll
            for (int reg = 0; reg < 4; reg++)
                a_buf[(size_t)(tokD0 + reg) * DS + n] = fast_tanh(acc[t][reg] + bias);
        }
    } else {
        // ===== KM wave: K @ Bkm^T -> kpart (tiles 0-7), w logits (tiles 8-11) + softmax =====
        const int tok0 = (bid - NTOK/16) * 16;
        const int tokA = tok0 + L15;
        const int tokD0 = tok0 + quad * 4;

        const bfrag* Bkm = (const bfrag*)BkmU;
        bfrag bfA[4][4], bfB[4][4];
        load_group(Bkm, 0, L, bfA);
        load_group(Bkm, 4, L, bfB);

        const int s = skill[tokA];
        const float* kp = k_emb + (size_t)s * DS + quad * 8;
        bfrag Kf[4];
        #pragma unroll
        for (int ki = 0; ki < 4; ki++) {
            const f32x4* b = (const f32x4*)(kp + ki * 32);
            Kf[ki] = mk_frag(b[0], b[1]);
        }

        __shared__ float wl[16][52];

        f32x4 acc[4];
        #pragma unroll
        for (int t = 0; t < 4; t++) acc[t] = (f32x4){0.f,0.f,0.f,0.f};
        mfma_group(Kf, bfA, acc);
        load_group(Bkm, 8, L, bfA);
        #pragma unroll
        for (int t = 0; t < 4; t++) {
            const int n = t * 16 + L15;
            #pragma unroll
            for (int reg = 0; reg < 4; reg++)
                kp_buf[(size_t)(tokD0 + reg) * DS + n] = acc[t][reg];
        }

        #pragma unroll
        for (int t = 0; t < 4; t++) acc[t] = (f32x4){0.f,0.f,0.f,0.f};
        mfma_group(Kf, bfB, acc);
        #pragma unroll
        for (int t = 0; t < 4; t++) {
            const int n = (4 + t) * 16 + L15;
            #pragma unroll
            for (int reg = 0; reg < 4; reg++)
                kp_buf[(size_t)(tokD0 + reg) * DS + n] = acc[t][reg];
        }

        #pragma unroll
        for (int t = 0; t < 4; t++) acc[t] = (f32x4){0.f,0.f,0.f,0.f};
        mfma_group(Kf, bfA, acc);
        #pragma unroll
        for (int t = 0; t < 4; t++) {
            const int c = (8 + t) * 16 + L15 - 128;
            if (c < SM) {
                #pragma unroll
                for (int reg = 0; reg < 4; reg++)
                    wl[quad * 4 + reg][c] = acc[t][reg];
            }
        }
        __syncthreads();
        if (L < 16) {
            float mx = -1e30f;
            for (int m = 0; m < SM; m++) mx = fmaxf(mx, wl[L][m]);
            float sum = 0.f;
            float ex[SM];
            for (int m = 0; m < SM; m++) { ex[m] = fast_exp(wl[L][m] - mx); sum += ex[m]; }
            const float inv = fast_rcp(sum);
            float* wp = w_buf + (size_t)(tok0 + L) * SM;
            for (int m = 0; m < SM; m++) wp[m] = ex[m] * inv;
        }
    }
}

// ---------------- K2: scan; block = (b, d-half), 10 waves x 5 m-rows; LDS-reduced reads ----------------
// Partial rd per wave stashed in LDS; every CH steps the block reduces across waves
// and writes FINAL reads to reads_buf. No part_buf, no combine in K3.
__global__ __launch_bounds__(64*NWV) void k2_scan(
    const float* __restrict__ w_buf, const float* __restrict__ e_buf,
    const float* __restrict__ a_buf, const float* __restrict__ Mv0,
    float* __restrict__ reads_buf)
{
    const int b    = blockIdx.x >> 1;
    const int dh   = blockIdx.x & 1;
    const int wave = threadIdx.x >> 6;    // m-group 0..9
    const int lane = threadIdx.x & 63;
    const int d    = dh * 64 + lane;
    const int m0   = wave * MPG;
    const int base = b * Tn;

    __shared__ float stash[NWV][CH][64];

    float Mv[MPG];
    #pragma unroll
    for (int m = 0; m < MPG; m++) Mv[m] = Mv0[(size_t)(m0+m)*DS + d];

    // 4 stages x 2 timesteps ring: 8 timesteps in flight
    float se[4][2], sa[4][2], sw[4][2][MPG];

    #define LOADST(ST, T)                                                      \
        { const int tc_ = ((T) < Tn) ? (T) : 0;                                \
          _Pragma("unroll")                                                    \
          for (int q_ = 0; q_ < 2; q_++) {                                     \
              const int tf_ = base + tc_ + q_;                                 \
              se[ST][q_] = e_buf[(size_t)tf_*DS + d];                          \
              sa[ST][q_] = a_buf[(size_t)tf_*DS + d];                          \
              _Pragma("unroll")                                                \
              for (int m_ = 0; m_ < MPG; m_++)                                 \
                  sw[ST][q_][m_] = w_buf[(size_t)tf_*SM + m0 + m_];            \
          } }

    LOADST(0, 0) LOADST(1, 2) LOADST(2, 4) LOADST(3, 6)

    for (int c = 0; c < Tn/CH; c++) {          // 10 chunks of 20 steps
        #pragma unroll
        for (int s = 0; s < CH/2; s++) {       // 10 stages of 2 steps
            const int t0 = c*CH + s*2;
            const int st = (c*(CH/2) + s) & 3;
            #pragma unroll
            for (int q = 0; q < 2; q++) {
                const float ev = se[st][q], av = sa[st][q];
                float rd = 0.f;
                #pragma unroll
                for (int m = 0; m < MPG; m++) {
                    const float wm = sw[st][q][m];
                    rd = fmaf(wm, Mv[m], rd);                           // read uses OLD Mv
                    Mv[m] = fmaf(-wm, fmaf(ev, Mv[m], -av), Mv[m]);     // Mv*(1-w*e)+w*a
                }
                stash[wave][s*2+q][lane] = rd;
            }
            LOADST(st, t0 + 8)
        }
        __syncthreads();
        // reduce across the 10 waves: CH*64 = 1280 slots, 640 threads x 2
        #pragma unroll
        for (int q = 0; q < 2; q++) {
            const int slot = threadIdx.x + q * (64*NWV);
            const int tl = slot >> 6, dl = slot & 63;
            float sum = 0.f;
            #pragma unroll
            for (int g = 0; g < NWV; g++) sum += stash[g][tl][dl];
            reads_buf[(size_t)(base + c*CH + tl)*DS + dh*64 + dl] = sum;
        }
        __syncthreads();
    }
    #undef LOADST
}

// ---------------- K3: 1-wave blocks; f-GEMM from reads_buf + pred gather-dot ----------------
__global__ __launch_bounds__(64) void k3_gemm(
    const float* __restrict__ reads_buf, const float* __restrict__ kp_buf,
    const unsigned int* __restrict__ Bf0U, const float* __restrict__ fB,
    const float* __restrict__ pW, const float* __restrict__ pB,
    const int* __restrict__ skill, float* __restrict__ out)
{
    const int L = threadIdx.x, L15 = L & 15, quad = L >> 4;
    const int tok0 = blockIdx.x * 16;
    const int tokA = tok0 + L15;
    const int tokD0 = tok0 + quad * 4;

    const bfrag* Bf0 = (const bfrag*)Bf0U;
    bfrag bfA[4][4], bfB[4][4];
    load_group(Bf0, 0, L, bfA);
    load_group(Bf0, 4, L, bfB);

    // A-frags straight from reads_buf
    bfrag Rf[4];
    #pragma unroll
    for (int ki = 0; ki < 4; ki++) {
        const f32x4* q4 = (const f32x4*)(reads_buf + (size_t)tokA * DS + ki * 32 + quad * 8);
        Rf[ki] = mk_frag(q4[0], q4[1]);
    }

    float f[4][8];   // [reg][nt]
    f32x4 acc[4];

    #pragma unroll
    for (int t = 0; t < 4; t++) acc[t] = (f32x4){0.f,0.f,0.f,0.f};
    mfma_group(Rf, bfA, acc);
    #pragma unroll
    for (int t = 0; t < 4; t++) {
        const int n = t * 16 + L15;
        const float fb = fB[n];
        #pragma unroll
        for (int reg = 0; reg < 4; reg++)
            f[reg][t] = fast_tanh(acc[t][reg] + kp_buf[(size_t)(tokD0 + reg) * DS + n] + fb);
    }

    #pragma unroll
    for (int t = 0; t < 4; t++) acc[t] = (f32x4){0.f,0.f,0.f,0.f};
    mfma_group(Rf, bfB, acc);
    #pragma unroll
    for (int t = 0; t < 4; t++) {
        const int n = (4 + t) * 16 + L15;
        const float fb = fB[n];
        #pragma unroll
        for (int reg = 0; reg < 4; reg++)
            f[reg][4 + t] = fast_tanh(acc[t][reg] + kp_buf[(size_t)(tokD0 + reg) * DS + n] + fb);
    }

    // pred: per D-row token, dot(f, pW[ix]) reduced over the 16 lanes (L15)
    #pragma unroll
    for (int reg = 0; reg < 4; reg++) {
        const int tok = tokD0 + reg;
        const int t = tok % Tn;
        const bool act = (t < Tn - 1);
        int sn = 0, ix = 0;
        float contrib = 0.f;
        if (act) {
            sn = skill[tok + 1];
            ix = (sn < NUMC) ? sn : (NUMC - 1);
            const float* pr = pW + (size_t)ix * DS + L15;
            #pragma unroll
            for (int nt = 0; nt < 8; nt++)
                contrib = fmaf(f[reg][nt], pr[nt * 16], contrib);
        }
        #pragma unroll
        for (int msk = 1; msk <= 8; msk <<= 1)
            contrib += __shfl_xor(contrib, msk);
        if (act && L15 == 0) {
            const float val = contrib + pB[ix];
            const float prd = (sn < NUMC) ? fast_sigmoid(val) : 0.f;
            out[(size_t)(tok / Tn) * (Tn - 1) + t] = prd;
        }
    }
}

extern "C" void kernel_launch(void* const* d_in, const int* in_sizes, int n_in,
                              void* d_out, int out_size, void* d_ws, size_t ws_size,
                              hipStream_t stream)
{
    const int*   skill  = (const int*)  d_in[0];
    const int*   answer = (const int*)  d_in[1];
    const float* k_emb  = (const float*)d_in[2];
    const float* v_emb  = (const float*)d_in[3];
    const float* Mk     = (const float*)d_in[4];
    const float* Mv0    = (const float*)d_in[5];
    const float* f_W    = (const float*)d_in[6];
    const float* f_b    = (const float*)d_in[7];
    const float* p_W    = (const float*)d_in[8];
    const float* p_b    = (const float*)d_in[9];
    const float* e_W    = (const float*)d_in[10];
    const float* e_b    = (const float*)d_in[11];
    const float* a_W    = (const float*)d_in[12];
    const float* a_b    = (const float*)d_in[13];
    float* out = (float*)d_out;

    float* ws        = (float*)d_ws;
    float* w_buf     = ws;                                  // NTOK*SM
    float* e_buf     = w_buf     + (size_t)NTOK*SM;         // NTOK*DS
    float* a_buf     = e_buf     + (size_t)NTOK*DS;
    float* kp_buf    = a_buf     + (size_t)NTOK*DS;
    float* reads_buf = kp_buf    + (size_t)NTOK*DS;         // NTOK*DS
    unsigned int* BeaU = (unsigned int*)(reads_buf + (size_t)NTOK*DS);
    unsigned int* BkmU = BeaU + 4096 * 4;
    unsigned int* Bf0U = BkmU + 3072 * 4;
    // total ~29 MB of d_ws

    k0_cast<<<36, 256, 0, stream>>>(e_W, a_W, f_W, Mk, BeaU, BkmU, Bf0U);
    k1_gemm<<<2*(NTOK/16), 64, 0, stream>>>(skill, answer, k_emb, v_emb,
        BeaU, BkmU, e_b, a_b, w_buf, e_buf, a_buf, kp_buf);
    k2_scan<<<Bsz*2, 64*NWV, 0, stream>>>(w_buf, e_buf, a_buf, Mv0, reads_buf);
    k3_gemm<<<NTOK/16, 64, 0, stream>>>(reads_buf, kp_buf, Bf0U, f_b,
        p_W, p_b, skill, out);
}

// Round 6
// 172.388 us; speedup vs baseline: 1.7103x; 1.7103x over previous
//
#include <hip/hip_runtime.h>
#include <math.h>

#define Bsz 64
#define Tn 200
#define NUMC 2000
#define DS 128
#define SM 50
#define NTOK (Bsz*Tn)
#define WG2 10       // m-groups in scan
#define MPG2 5       // m per group (WG2*MPG2 == SM)

typedef __attribute__((ext_vector_type(8))) short bfrag;
typedef __attribute__((ext_vector_type(4))) float f32x4;
typedef __attribute__((ext_vector_type(4))) unsigned int u32x4;

__device__ __forceinline__ unsigned short f2bf(float x) {
    unsigned int u = __builtin_bit_cast(unsigned int, x);
    u = u + 0x7fffu + ((u >> 16) & 1u);   // RNE
    return (unsigned short)(u >> 16);
}
__device__ __forceinline__ unsigned int pack2(float a, float b) {
    return (unsigned int)f2bf(a) | ((unsigned int)f2bf(b) << 16);
}
__device__ __forceinline__ float bf2f(unsigned int u) {
    return __builtin_bit_cast(float, u << 16);
}
__device__ __forceinline__ bfrag mk_frag(f32x4 x, f32x4 y) {
    u32x4 t;
    t[0] = pack2(x[0], x[1]); t[1] = pack2(x[2], x[3]);
    t[2] = pack2(y[0], y[1]); t[3] = pack2(y[2], y[3]);
    return __builtin_bit_cast(bfrag, t);
}

// fast transcendentals: v_exp_f32 / v_rcp_f32 (~1e-6 rel err, invisible at bf16 grade)
__device__ __forceinline__ float fast_exp(float x)  { return __builtin_amdgcn_exp2f(x * 1.44269504f); }
__device__ __forceinline__ float fast_rcp(float x)  { return __builtin_amdgcn_rcpf(x); }
__device__ __forceinline__ float fast_sigmoid(float x) { return fast_rcp(1.f + fast_exp(-x)); }
__device__ __forceinline__ float fast_tanh(float x) { return 1.f - 2.f * fast_rcp(fast_exp(2.f * x) + 1.f); }

// Build a 4-tile B-frag group straight from fp32 rows (in-register cast; no k0 pass).
// Frag layout: lane L holds W[n = nt*16 + (L&15)][k = ki*32 + (L>>4)*8 + j], j=0..7.
__device__ __forceinline__ void load_group_ea(
    const float* __restrict__ eW, const float* __restrict__ aW,
    int nt0, int L15, int quad, bfrag bf[4][4])
{
    #pragma unroll
    for (int t = 0; t < 4; t++) {
        const int n = (nt0 + t) * 16 + L15;          // tile is 16-aligned; boundary at 128
        const float* row = (n < 128) ? (eW + (size_t)n * DS) : (aW + (size_t)(n - 128) * DS);
        #pragma unroll
        for (int ki = 0; ki < 4; ki++) {
            const float* p = row + ki * 32 + quad * 8;
            bf[t][ki] = mk_frag(*(const f32x4*)p, *(const f32x4*)(p + 4));
        }
    }
}
__device__ __forceinline__ void load_group_km(
    const float* __restrict__ fW, const float* __restrict__ Mk,
    int nt0, int L15, int quad, bfrag bf[4][4])
{
    #pragma unroll
    for (int t = 0; t < 4; t++) {
        const int n = (nt0 + t) * 16 + L15;
        const bool valid = n < 128 + SM;             // rows 178..191 are zero-pad
        const float* row = (n < 128) ? (fW + (size_t)n * (2*DS) + DS)
                                     : (Mk + (size_t)(n - 128) * DS);
        #pragma unroll
        for (int ki = 0; ki < 4; ki++) {
            const float* p = row + ki * 32 + quad * 8;
            f32x4 x = valid ? *(const f32x4*)p       : (f32x4){0.f,0.f,0.f,0.f};
            f32x4 y = valid ? *(const f32x4*)(p + 4) : (f32x4){0.f,0.f,0.f,0.f};
            bf[t][ki] = mk_frag(x, y);
        }
    }
}
__device__ __forceinline__ void load_group_f0(
    const float* __restrict__ fW, int nt0, int L15, int quad, bfrag bf[4][4])
{
    #pragma unroll
    for (int t = 0; t < 4; t++) {
        const int n = (nt0 + t) * 16 + L15;
        const float* row = fW + (size_t)n * (2*DS);
        #pragma unroll
        for (int ki = 0; ki < 4; ki++) {
            const float* p = row + ki * 32 + quad * 8;
            bf[t][ki] = mk_frag(*(const f32x4*)p, *(const f32x4*)(p + 4));
        }
    }
}
__device__ __forceinline__ void mfma_group(const bfrag A[4], const bfrag bf[4][4], f32x4 acc[4]) {
    #pragma unroll
    for (int ki = 0; ki < 4; ki++)
        #pragma unroll
        for (int t = 0; t < 4; t++)
            acc[t] = __builtin_amdgcn_mfma_f32_16x16x32_bf16(A[ki], bf[t][ki], acc[t], 0, 0, 0);
}

// ---------------- K1: 1-wave blocks; bid<800 -> EA wave, else KM wave ----------------
__global__ __launch_bounds__(64) void k1_gemm(
    const int* __restrict__ skill, const int* __restrict__ answer,
    const float* __restrict__ k_emb, const float* __restrict__ v_emb,
    const float* __restrict__ eW, const float* __restrict__ aW,
    const float* __restrict__ fW, const float* __restrict__ Mk,
    const float* __restrict__ eB, const float* __restrict__ aB,
    float* __restrict__ w_buf, float* __restrict__ e_buf,
    float* __restrict__ a_buf, float* __restrict__ kp_buf)
{
    const int bid = blockIdx.x;
    const int L = threadIdx.x, L15 = L & 15, quad = L >> 4;

    if (bid < NTOK/16) {
        // ===== EA wave: V @ Bea^T -> e (tiles 0-7, sigmoid), a (tiles 8-15, tanh) =====
        const int tok0 = bid * 16;
        const int tokA = tok0 + L15;
        const int tokD0 = tok0 + quad * 4;

        bfrag bfA[4][4], bfB[4][4];
        load_group_ea(eW, aW, 0, L15, quad, bfA);
        load_group_ea(eW, aW, 4, L15, quad, bfB);

        const int s  = skill[tokA];
        const int an = answer[tokA];
        const int ax = (an == 2) ? 1 : an;
        const float* vp = v_emb + ((size_t)(s + NUMC * ax)) * DS + quad * 8;
        bfrag Vf[4];
        #pragma unroll
        for (int ki = 0; ki < 4; ki++) {
            const f32x4* a = (const f32x4*)(vp + ki * 32);
            Vf[ki] = mk_frag(a[0], a[1]);
        }

        f32x4 acc[4];
        #pragma unroll
        for (int t = 0; t < 4; t++) acc[t] = (f32x4){0.f,0.f,0.f,0.f};
        mfma_group(Vf, bfA, acc);
        load_group_ea(eW, aW, 8, L15, quad, bfA);
        #pragma unroll
        for (int t = 0; t < 4; t++) {
            const int n = t * 16 + L15;
            const float bias = eB[n];
            #pragma unroll
            for (int reg = 0; reg < 4; reg++)
                e_buf[(size_t)(tokD0 + reg) * DS + n] = fast_sigmoid(acc[t][reg] + bias);
        }

        #pragma unroll
        for (int t = 0; t < 4; t++) acc[t] = (f32x4){0.f,0.f,0.f,0.f};
        mfma_group(Vf, bfB, acc);
        load_group_ea(eW, aW, 12, L15, quad, bfB);
        #pragma unroll
        for (int t = 0; t < 4; t++) {
            const int n = (4 + t) * 16 + L15;
            const float bias = eB[n];
            #pragma unroll
            for (int reg = 0; reg < 4; reg++)
                e_buf[(size_t)(tokD0 + reg) * DS + n] = fast_sigmoid(acc[t][reg] + bias);
        }

        #pragma unroll
        for (int t = 0; t < 4; t++) acc[t] = (f32x4){0.f,0.f,0.f,0.f};
        mfma_group(Vf, bfA, acc);
        #pragma unroll
        for (int t = 0; t < 4; t++) {
            const int n = t * 16 + L15;
            const float bias = aB[n];
            #pragma unroll
            for (int reg = 0; reg < 4; reg++)
                a_buf[(size_t)(tokD0 + reg) * DS + n] = fast_tanh(acc[t][reg] + bias);
        }

        #pragma unroll
        for (int t = 0; t < 4; t++) acc[t] = (f32x4){0.f,0.f,0.f,0.f};
        mfma_group(Vf, bfB, acc);
        #pragma unroll
        for (int t = 0; t < 4; t++) {
            const int n = (4 + t) * 16 + L15;
            const float bias = aB[n];
            #pragma unroll
            for (int reg = 0; reg < 4; reg++)
                a_buf[(size_t)(tokD0 + reg) * DS + n] = fast_tanh(acc[t][reg] + bias);
        }
    } else {
        // ===== KM wave: K @ Bkm^T -> kpart (tiles 0-7), w logits (tiles 8-11) + softmax =====
        const int tok0 = (bid - NTOK/16) * 16;
        const int tokA = tok0 + L15;
        const int tokD0 = tok0 + quad * 4;

        bfrag bfA[4][4], bfB[4][4];
        load_group_km(fW, Mk, 0, L15, quad, bfA);
        load_group_km(fW, Mk, 4, L15, quad, bfB);

        const int s = skill[tokA];
        const float* kp = k_emb + (size_t)s * DS + quad * 8;
        bfrag Kf[4];
        #pragma unroll
        for (int ki = 0; ki < 4; ki++) {
            const f32x4* b = (const f32x4*)(kp + ki * 32);
            Kf[ki] = mk_frag(b[0], b[1]);
        }

        __shared__ float wl[16][52];

        f32x4 acc[4];
        #pragma unroll
        for (int t = 0; t < 4; t++) acc[t] = (f32x4){0.f,0.f,0.f,0.f};
        mfma_group(Kf, bfA, acc);
        load_group_km(fW, Mk, 8, L15, quad, bfA);
        #pragma unroll
        for (int t = 0; t < 4; t++) {
            const int n = t * 16 + L15;
            #pragma unroll
            for (int reg = 0; reg < 4; reg++)
                kp_buf[(size_t)(tokD0 + reg) * DS + n] = acc[t][reg];
        }

        #pragma unroll
        for (int t = 0; t < 4; t++) acc[t] = (f32x4){0.f,0.f,0.f,0.f};
        mfma_group(Kf, bfB, acc);
        #pragma unroll
        for (int t = 0; t < 4; t++) {
            const int n = (4 + t) * 16 + L15;
            #pragma unroll
            for (int reg = 0; reg < 4; reg++)
                kp_buf[(size_t)(tokD0 + reg) * DS + n] = acc[t][reg];
        }

        #pragma unroll
        for (int t = 0; t < 4; t++) acc[t] = (f32x4){0.f,0.f,0.f,0.f};
        mfma_group(Kf, bfA, acc);
        #pragma unroll
        for (int t = 0; t < 4; t++) {
            const int c = (8 + t) * 16 + L15 - 128;
            if (c < SM) {
                #pragma unroll
                for (int reg = 0; reg < 4; reg++)
                    wl[quad * 4 + reg][c] = acc[t][reg];
            }
        }
        __syncthreads();
        if (L < 16) {
            float mx = -1e30f;
            for (int m = 0; m < SM; m++) mx = fmaxf(mx, wl[L][m]);
            float sum = 0.f;
            float ex[SM];
            for (int m = 0; m < SM; m++) { ex[m] = fast_exp(wl[L][m] - mx); sum += ex[m]; }
            const float inv = fast_rcp(sum);
            float* wp = w_buf + (size_t)(tok0 + L) * SM;
            for (int m = 0; m < SM; m++) wp[m] = ex[m] * inv;
        }
    }
}

// ---------------- K2: scan; (b, d-half, m-group) 1-wave blocks; bf16 partial writes ----------------
__global__ __launch_bounds__(64) void k2_scan(
    const float* __restrict__ w_buf, const float* __restrict__ e_buf,
    const float* __restrict__ a_buf, const float* __restrict__ Mv0,
    unsigned short* __restrict__ part16)
{
    const int bi   = blockIdx.x;
    const int b    = bi / (2*WG2);
    const int r    = bi % (2*WG2);
    const int dh   = r / WG2;
    const int mg   = r % WG2;
    const int lane = threadIdx.x;
    const int d    = dh*64 + lane;
    const int m0   = mg * MPG2;
    const int base = b * Tn;

    float Mv[MPG2];
    #pragma unroll
    for (int m = 0; m < MPG2; m++) Mv[m] = Mv0[(size_t)(m0+m)*DS + d];

    unsigned short* pout = part16 + (size_t)mg * NTOK * DS;

    // 4 stages x 2 timesteps ring: 8 timesteps in flight
    float se[4][2], sa[4][2], sw[4][2][MPG2];

    #define LOADST(ST, T)                                                      \
        { const int tc_ = ((T) < Tn) ? (T) : 0;                                \
          _Pragma("unroll")                                                    \
          for (int q_ = 0; q_ < 2; q_++) {                                     \
              const int tf_ = base + tc_ + q_;                                 \
              se[ST][q_] = e_buf[(size_t)tf_*DS + d];                          \
              sa[ST][q_] = a_buf[(size_t)tf_*DS + d];                          \
              _Pragma("unroll")                                                \
              for (int m_ = 0; m_ < MPG2; m_++)                                \
                  sw[ST][q_][m_] = w_buf[(size_t)tf_*SM + m0 + m_];            \
          } }

    LOADST(0, 0) LOADST(1, 2) LOADST(2, 4) LOADST(3, 6)

    for (int i = 0; i < 25; i++) {
        const int tb = i * 8;
        #pragma unroll
        for (int sub = 0; sub < 4; sub++) {
            const int t0 = tb + sub * 2;
            #pragma unroll
            for (int q = 0; q < 2; q++) {
                const float ev = se[sub][q], av = sa[sub][q];
                float rd = 0.f;
                #pragma unroll
                for (int m = 0; m < MPG2; m++) {
                    const float wm = sw[sub][q][m];
                    rd = fmaf(wm, Mv[m], rd);                               // read uses OLD Mv
                    Mv[m] = fmaf(-wm, fmaf(ev, Mv[m], -av), Mv[m]);         // Mv*(1-w*e)+w*a
                }
                pout[(size_t)(base + t0 + q)*DS + d] = f2bf(rd);
            }
            LOADST(sub, t0 + 8)
        }
    }
    #undef LOADST
}

// ---------------- K3: 1-wave blocks; combine bf16 partials + f-GEMM + pred gather-dot ----------------
__global__ __launch_bounds__(64) void k3_gemm(
    const unsigned short* __restrict__ part16, const float* __restrict__ kp_buf,
    const float* __restrict__ fW, const float* __restrict__ fB,
    const float* __restrict__ pW, const float* __restrict__ pB,
    const int* __restrict__ skill, float* __restrict__ out)
{
    const int L = threadIdx.x, L15 = L & 15, quad = L >> 4;
    const int tok0 = blockIdx.x * 16;
    const int tokA = tok0 + L15;
    const int tokD0 = tok0 + quad * 4;

    bfrag bfA[4][4], bfB[4][4];
    load_group_f0(fW, 0, L15, quad, bfA);
    load_group_f0(fW, 4, L15, quad, bfB);

    // A-frags: reads = sum of WG2 bf16 partials, repacked to bf16
    bfrag Rf[4];
    #pragma unroll
    for (int ki = 0; ki < 4; ki++) {
        const unsigned short* p0 = part16 + (size_t)tokA * DS + ki * 32 + quad * 8;
        float s0=0,s1=0,s2=0,s3=0,s4=0,s5=0,s6=0,s7=0;
        #pragma unroll
        for (int g = 0; g < WG2; g++) {
            u32x4 v = *(const u32x4*)(p0 + (size_t)g * NTOK * DS);
            s0 += bf2f(v[0] & 0xffffu); s1 += bf2f(v[0] >> 16);
            s2 += bf2f(v[1] & 0xffffu); s3 += bf2f(v[1] >> 16);
            s4 += bf2f(v[2] & 0xffffu); s5 += bf2f(v[2] >> 16);
            s6 += bf2f(v[3] & 0xffffu); s7 += bf2f(v[3] >> 16);
        }
        Rf[ki] = mk_frag((f32x4){s0,s1,s2,s3}, (f32x4){s4,s5,s6,s7});
    }

    float f[4][8];   // [reg][nt]
    f32x4 acc[4];

    #pragma unroll
    for (int t = 0; t < 4; t++) acc[t] = (f32x4){0.f,0.f,0.f,0.f};
    mfma_group(Rf, bfA, acc);
    #pragma unroll
    for (int t = 0; t < 4; t++) {
        const int n = t * 16 + L15;
        const float fb = fB[n];
        #pragma unroll
        for (int reg = 0; reg < 4; reg++)
            f[reg][t] = fast_tanh(acc[t][reg] + kp_buf[(size_t)(tokD0 + reg) * DS + n] + fb);
    }

    #pragma unroll
    for (int t = 0; t < 4; t++) acc[t] = (f32x4){0.f,0.f,0.f,0.f};
    mfma_group(Rf, bfB, acc);
    #pragma unroll
    for (int t = 0; t < 4; t++) {
        const int n = (4 + t) * 16 + L15;
        const float fb = fB[n];
        #pragma unroll
        for (int reg = 0; reg < 4; reg++)
            f[reg][4 + t] = fast_tanh(acc[t][reg] + kp_buf[(size_t)(tokD0 + reg) * DS + n] + fb);
    }

    // pred: per D-row token, dot(f, pW[ix]) reduced over the 16 lanes (L15)
    #pragma unroll
    for (int reg = 0; reg < 4; reg++) {
        const int tok = tokD0 + reg;
        const int t = tok % Tn;
        const bool act = (t < Tn - 1);
        int sn = 0, ix = 0;
        float contrib = 0.f;
        if (act) {
            sn = skill[tok + 1];
            ix = (sn < NUMC) ? sn : (NUMC - 1);
            const float* pr = pW + (size_t)ix * DS + L15;
            #pragma unroll
            for (int nt = 0; nt < 8; nt++)
                contrib = fmaf(f[reg][nt], pr[nt * 16], contrib);
        }
        #pragma unroll
        for (int msk = 1; msk <= 8; msk <<= 1)
            contrib += __shfl_xor(contrib, msk);
        if (act && L15 == 0) {
            const float val = contrib + pB[ix];
            const float prd = (sn < NUMC) ? fast_sigmoid(val) : 0.f;
            out[(size_t)(tok / Tn) * (Tn - 1) + t] = prd;
        }
    }
}

extern "C" void kernel_launch(void* const* d_in, const int* in_sizes, int n_in,
                              void* d_out, int out_size, void* d_ws, size_t ws_size,
                              hipStream_t stream)
{
    const int*   skill  = (const int*)  d_in[0];
    const int*   answer = (const int*)  d_in[1];
    const float* k_emb  = (const float*)d_in[2];
    const float* v_emb  = (const float*)d_in[3];
    const float* Mk     = (const float*)d_in[4];
    const float* Mv0    = (const float*)d_in[5];
    const float* f_W    = (const float*)d_in[6];
    const float* f_b    = (const float*)d_in[7];
    const float* p_W    = (const float*)d_in[8];
    const float* p_b    = (const float*)d_in[9];
    const float* e_W    = (const float*)d_in[10];
    const float* e_b    = (const float*)d_in[11];
    const float* a_W    = (const float*)d_in[12];
    const float* a_b    = (const float*)d_in[13];
    float* out = (float*)d_out;

    float* ws     = (float*)d_ws;
    float* w_buf  = ws;                                    // NTOK*SM
    float* e_buf  = w_buf  + (size_t)NTOK*SM;              // NTOK*DS
    float* a_buf  = e_buf  + (size_t)NTOK*DS;
    float* kp_buf = a_buf  + (size_t)NTOK*DS;
    unsigned short* part16 = (unsigned short*)(kp_buf + (size_t)NTOK*DS);  // WG2*NTOK*DS ushort
    // total ~55 MB of d_ws

    k1_gemm<<<2*(NTOK/16), 64, 0, stream>>>(skill, answer, k_emb, v_emb,
        e_W, a_W, f_W, Mk, e_b, a_b, w_buf, e_buf, a_buf, kp_buf);
    k2_scan<<<Bsz*2*WG2, 64, 0, stream>>>(w_buf, e_buf, a_buf, Mv0, part16);
    k3_gemm<<<NTOK/16, 64, 0, stream>>>(part16, kp_buf, f_W, f_b,
        p_W, p_b, skill, out);
}